// Round 11
// baseline (618.603 us; speedup 1.0000x reference)
//
#include <hip/hip_runtime.h>
#include <hip/hip_bf16.h>
#include <math.h>

#define DD 128
#define EPSBN 1e-5f

typedef float f2 __attribute__((ext_vector_type(2)));

// ---------- small helpers ----------
__device__ __forceinline__ float4 f4_add(float4 a, float4 b) {
    return make_float4(a.x + b.x, a.y + b.y, a.z + b.z, a.w + b.w);
}
__device__ __forceinline__ float4 f4_fma(float a, float4 b, float4 c) {
    c.x = fmaf(a, b.x, c.x); c.y = fmaf(a, b.y, c.y);
    c.z = fmaf(a, b.z, c.z); c.w = fmaf(a, b.w, c.w);
    return c;
}
__device__ __forceinline__ float leakyf(float v, float s) { return v > 0.f ? v : s * v; }

__device__ __forceinline__ unsigned short f2bf(float f) {   // RNE
    unsigned u = __float_as_uint(f);
    return (unsigned short)((u + 0x7fffu + ((u >> 16) & 1u)) >> 16);
}
__device__ __forceinline__ f2 bfu2f2(unsigned u) {          // packed 2×bf16 -> 2×f32
    f2 r;
    r.x = __uint_as_float(u << 16);
    r.y = __uint_as_float(u & 0xFFFF0000u);
    return r;
}
__device__ __forceinline__ f2 leaky2(f2 v, float s) {
    f2 z = (f2)0.f;
    return __builtin_elementwise_max(v, z) + s * __builtin_elementwise_min(v, z);
}

// ---------- prep: transpose conv_w AND init counts(=1: self-loop)/stats ----------
__global__ __launch_bounds__(256) void k_prep(const float* __restrict__ conv_w, float* __restrict__ wT,
                                              int* __restrict__ counts, float* __restrict__ stats,
                                              int n, int nstats) {
    int idx = blockIdx.x * 256 + threadIdx.x;
    if (idx < 3 * 128 * 128) {
        int k = idx >> 14;
        int r = idx & 16383;
        int ci = r >> 7, co = r & 127;
        wT[idx] = conv_w[(size_t)co * 384 + ci * 3 + k];
    }
    int z = idx - 3 * 128 * 128;
    if (z >= 0) {
        if (z < n) counts[z] = 1;             // self-loop pre-count
        else if (z - n < nstats) stats[z - n] = 0.f;
    }
}

// ---------- XR = x@W_r + b_r (fp32); XLh = bf16(x@W_l + b_l) ----------
__global__ __launch_bounds__(256) void k_gemm_xlxr(
    const float* __restrict__ x, const float* __restrict__ Wl, const float* __restrict__ bl,
    const float* __restrict__ Wr, const float* __restrict__ br,
    float* __restrict__ XR, unsigned short* __restrict__ XLh, int n)
{
    __shared__ float As[64 * 33];
    __shared__ float Bs[32 * 256];
    int tid = threadIdx.x;
    int r0 = blockIdx.x * 64;
    int tx = tid & 31, ty = tid >> 5;

    float4 accL[8], accR[8];
    #pragma unroll
    for (int j = 0; j < 8; ++j) {
        accL[j] = make_float4(0.f, 0.f, 0.f, 0.f);
        accR[j] = make_float4(0.f, 0.f, 0.f, 0.f);
    }

    for (int k0 = 0; k0 < 128; k0 += 32) {
        for (int idx = tid; idx < 64 * 32; idx += 256) {
            int lrow = idx >> 5, kk = idx & 31;
            int g = r0 + lrow;
            As[lrow * 33 + kk] = (g < n) ? x[(size_t)g * DD + k0 + kk] : 0.f;
        }
        for (int idx = tid; idx < 2048; idx += 256) {
            int kk = idx >> 6, co4 = idx & 63;
            float4 v;
            if (co4 < 32) v = ((const float4*)Wl)[(size_t)(k0 + kk) * 32 + co4];
            else          v = ((const float4*)Wr)[(size_t)(k0 + kk) * 32 + (co4 - 32)];
            ((float4*)Bs)[kk * 64 + co4] = v;
        }
        __syncthreads();

        #pragma unroll 4
        for (int kk = 0; kk < 32; ++kk) {
            float a[8];
            #pragma unroll
            for (int j = 0; j < 8; ++j) a[j] = As[(ty * 8 + j) * 33 + kk];
            float4 bL = ((float4*)Bs)[kk * 64 + tx];
            float4 bR = ((float4*)Bs)[kk * 64 + 32 + tx];
            #pragma unroll
            for (int j = 0; j < 8; ++j) {
                accL[j] = f4_fma(a[j], bL, accL[j]);
                accR[j] = f4_fma(a[j], bR, accR[j]);
            }
        }
        __syncthreads();
    }

    float4 blv = ((const float4*)bl)[tx];
    float4 brv = ((const float4*)br)[tx];
    #pragma unroll
    for (int j = 0; j < 8; ++j) {
        int row = r0 + ty * 8 + j;
        if (row < n) {
            float4 L4 = f4_add(accL[j], blv);
            ((float4*)(XR + (size_t)row * DD))[tx] = f4_add(accR[j], brv);
            uint2 hp;
            hp.x = (unsigned)f2bf(L4.x) | ((unsigned)f2bf(L4.y) << 16);
            hp.y = (unsigned)f2bf(L4.z) | ((unsigned)f2bf(L4.w) << 16);
            ((uint2*)(XLh + (size_t)row * DD))[tx] = hp;
        }
    }
}

// ---------- CSR build ----------
__global__ __launch_bounds__(256) void k_hist(const int* __restrict__ dst, int* __restrict__ counts, int e) {
    int idx = blockIdx.x * 256 + threadIdx.x;
    if (idx < e) atomicAdd(&counts[dst[idx]], 1);
}

// 3-stage parallel scan: chunk-local scan -> chunk-sum scan -> add-back
__global__ __launch_bounds__(256) void k_scan1(const int* __restrict__ counts,
                                               int* __restrict__ offsets, int* __restrict__ bsum, int n) {
    __shared__ int tmp[256];
    int t = threadIdx.x;
    int i = blockIdx.x * 256 + t;
    int v = (i < n) ? counts[i] : 0;
    tmp[t] = v;
    __syncthreads();
    for (int off = 1; off < 256; off <<= 1) {
        int u = (t >= off) ? tmp[t - off] : 0;
        __syncthreads();
        tmp[t] += u;
        __syncthreads();
    }
    if (i < n) offsets[i] = tmp[t] - v;          // exclusive within chunk
    if (t == 255) bsum[blockIdx.x] = tmp[255];   // chunk total
}

__global__ __launch_bounds__(1024) void k_scan2(int* __restrict__ bsum, int nchunks) {
    __shared__ int tmp[1024];
    int t = threadIdx.x;
    int v = (t < nchunks) ? bsum[t] : 0;
    tmp[t] = v;
    __syncthreads();
    for (int off = 1; off < 1024; off <<= 1) {
        int u = (t >= off) ? tmp[t - off] : 0;
        __syncthreads();
        tmp[t] += u;
        __syncthreads();
    }
    if (t < nchunks) bsum[t] = tmp[t] - v;       // exclusive chunk prefix
    if (t == 0) bsum[nchunks] = tmp[nchunks - 1]; // grand total
}

// writes the self-loop entry (-1, i) at each segment head; real edges start at o+1
__global__ __launch_bounds__(256) void k_scan3(int* __restrict__ offsets, int* __restrict__ cursor,
                                               const int* __restrict__ bsum, int2* __restrict__ epair,
                                               int n, int nchunks) {
    int i = blockIdx.x * 256 + threadIdx.x;
    if (i < n) {
        int o = offsets[i] + bsum[i >> 8];
        offsets[i] = o;
        epair[o] = make_int2(-1, i);   // self-loop first in segment (matches prior sum order)
        cursor[i] = o + 1;
    }
    if (i == n) offsets[n] = bsum[nchunks];
}

__global__ __launch_bounds__(256) void k_scatter(const int* __restrict__ src, const int* __restrict__ dst,
                                                 int* __restrict__ cursor, int2* __restrict__ epair, int e) {
    int idx = blockIdx.x * 256 + threadIdx.x;
    if (idx >= e) return;
    int d = dst[idx];
    int pos = atomicAdd(&cursor[d], 1);
    epair[pos] = make_int2(idx, src[idx]);
}

// ---------- fused GATv2: dual-stream wave-per-node-pair, fully pipelined ----------
// exp(l) without max subtraction is safe: logit sigma ~1.5, max over 850k edges ~8 << 88.
// R17: per-node serial chains (self-loop setup ~800cy, prologue ~600cy, tail edges
// ~500cy each) were ~half of k_gat's time (VALU 48%). Now:
//  - self-loop is an epair entry (eid=-1 -> attr gated 0); counts init 1; k_scan3 writes it.
//  - NO serial tail: gated groups (clamp idx to pe-1, gate exp to 0), ceil(cnt/4) groups.
//  - dual-stream: each wave processes adjacent node pair (A,B) with interleaved depth-1
//    pipelines sharing the loop counter -> ~10 loads in flight/wave, stalls decorrelate.
// Depth stays 1 per stream (depth-2 regressed: LDS attr write forced early vmcnt drain).

#define EPROJ(EB_, J_, EV_) {                                                   \
    const float4* e4_ = ((const float4*)(EB_)) + (J_) * 4;                      \
    float4 a0_ = e4_[0], a1_ = e4_[1], a2_ = e4_[2], a3_ = e4_[3];              \
    f2 v_ = (f2)0.f;                                                            \
    v_ = __builtin_elementwise_fma((f2)a0_.x, w2[0],  v_);                      \
    v_ = __builtin_elementwise_fma((f2)a0_.y, w2[1],  v_);                      \
    v_ = __builtin_elementwise_fma((f2)a0_.z, w2[2],  v_);                      \
    v_ = __builtin_elementwise_fma((f2)a0_.w, w2[3],  v_);                      \
    v_ = __builtin_elementwise_fma((f2)a1_.x, w2[4],  v_);                      \
    v_ = __builtin_elementwise_fma((f2)a1_.y, w2[5],  v_);                      \
    v_ = __builtin_elementwise_fma((f2)a1_.z, w2[6],  v_);                      \
    v_ = __builtin_elementwise_fma((f2)a1_.w, w2[7],  v_);                      \
    v_ = __builtin_elementwise_fma((f2)a2_.x, w2[8],  v_);                      \
    v_ = __builtin_elementwise_fma((f2)a2_.y, w2[9],  v_);                      \
    v_ = __builtin_elementwise_fma((f2)a2_.z, w2[10], v_);                      \
    v_ = __builtin_elementwise_fma((f2)a2_.w, w2[11], v_);                      \
    v_ = __builtin_elementwise_fma((f2)a3_.x, w2[12], v_);                      \
    v_ = __builtin_elementwise_fma((f2)a3_.y, w2[13], v_);                      \
    v_ = __builtin_elementwise_fma((f2)a3_.z, w2[14], v_);                      \
    v_ = __builtin_elementwise_fma((f2)a3_.w, w2[15], v_);                      \
    EV_ = v_; }

// load 4-edge group at scalar base q_ (indices clamped to PE_-1; gated in compute)
#define GAT_LOAD4G(q_, PE_, U0_, U1_, U2_, U3_, AV_) {                          \
    int q1_ = (q_) + 1 < (PE_) ? (q_) + 1 : (PE_) - 1;                          \
    int q2_ = (q_) + 2 < (PE_) ? (q_) + 2 : (PE_) - 1;                          \
    int q3_ = (q_) + 3 < (PE_) ? (q_) + 3 : (PE_) - 1;                          \
    int2 g0_ = epair[q_], g1_ = epair[q1_];                                     \
    int2 g2_ = epair[q2_], g3_ = epair[q3_];                                    \
    int s0_ = __builtin_amdgcn_readfirstlane(g0_.y);                            \
    int s1_ = __builtin_amdgcn_readfirstlane(g1_.y);                            \
    int s2_ = __builtin_amdgcn_readfirstlane(g2_.y);                            \
    int s3_ = __builtin_amdgcn_readfirstlane(g3_.y);                            \
    U0_ = XLu[(size_t)s0_ * 64 + lane];                                         \
    U1_ = XLu[(size_t)s1_ * 64 + lane];                                         \
    U2_ = XLu[(size_t)s2_ * 64 + lane];                                         \
    U3_ = XLu[(size_t)s3_ * 64 + lane];                                         \
    int ej_ = esel == 0 ? g0_.x : esel == 1 ? g1_.x : esel == 2 ? g2_.x : g3_.x;\
    AV_ = ej_ >= 0 ? edge_attr[(size_t)ej_ * 16 + ek] : 0.f; }

// compute group at scalar base BQ_; slots BQ_+s >= PE_ gated to 0
#define GAT_COMPUTE4G(BQ_, PE_, U0_, U1_, U2_, U3_, EB_, S_, AXY_, XR2_) {      \
    f2 x0_ = bfu2f2(U0_), x1_ = bfu2f2(U1_);                                    \
    f2 x2_ = bfu2f2(U2_), x3_ = bfu2f2(U3_);                                    \
    f2 ev0_, ev1_, ev2_, ev3_;                                                  \
    EPROJ(EB_, 0, ev0_); EPROJ(EB_, 1, ev1_);                                   \
    EPROJ(EB_, 2, ev2_); EPROJ(EB_, 3, ev3_);                                   \
    f2 m0_ = leaky2(x0_ + (XR2_) + ev0_, 0.2f);                                 \
    f2 m1_ = leaky2(x1_ + (XR2_) + ev1_, 0.2f);                                 \
    f2 m2_ = leaky2(x2_ + (XR2_) + ev2_, 0.2f);                                 \
    f2 m3_ = leaky2(x3_ + (XR2_) + ev3_, 0.2f);                                 \
    float l0_ = m0_.x * att2.x + m0_.y * att2.y;                                \
    float l1_ = m1_.x * att2.x + m1_.y * att2.y;                                \
    float l2_ = m2_.x * att2.x + m2_.y * att2.y;                                \
    float l3_ = m3_.x * att2.x + m3_.y * att2.y;                                \
    _Pragma("unroll")                                                           \
    for (int off_ = 32; off_ > 0; off_ >>= 1) {                                 \
        l0_ += __shfl_xor(l0_, off_, 64);                                       \
        l1_ += __shfl_xor(l1_, off_, 64);                                       \
        l2_ += __shfl_xor(l2_, off_, 64);                                       \
        l3_ += __shfl_xor(l3_, off_, 64);                                       \
    }                                                                           \
    float g0_ = (BQ_) + 0 < (PE_) ? __expf(l0_) : 0.f;                          \
    float g1_ = (BQ_) + 1 < (PE_) ? __expf(l1_) : 0.f;                          \
    float g2_ = (BQ_) + 2 < (PE_) ? __expf(l2_) : 0.f;                          \
    float g3_ = (BQ_) + 3 < (PE_) ? __expf(l3_) : 0.f;                          \
    S_ += (g0_ + g1_) + (g2_ + g3_);                                            \
    AXY_ = __builtin_elementwise_fma((f2)g0_, x0_, AXY_);                       \
    AXY_ = __builtin_elementwise_fma((f2)g1_, x1_, AXY_);                       \
    AXY_ = __builtin_elementwise_fma((f2)g2_, x2_, AXY_);                       \
    AXY_ = __builtin_elementwise_fma((f2)g3_, x3_, AXY_); }

__global__ __launch_bounds__(256) void k_gat(
    const unsigned short* __restrict__ XLh, const float* __restrict__ XR,
    const float* __restrict__ x,
    const int2* __restrict__ epair, const int* __restrict__ offsets,
    const float* __restrict__ edge_attr, const float* __restrict__ We,
    const float* __restrict__ att, const float* __restrict__ bias_gat,
    const float* __restrict__ weight1, float* __restrict__ Z,
    float* __restrict__ p1, float* __restrict__ q1, int n, int nwaves)
{
    __shared__ float ebuf[4][4][64];   // [wave][A0,A1,B0,B1][4 edges * 16 attrs]
    __shared__ f2 brs[4][64];          // BN1 stats block reduce
    __shared__ f2 brq[4][64];
    int wv   = threadIdx.x >> 6;
    int wid  = blockIdx.x * 4 + wv;
    int lane = threadIdx.x & 63;
    int c = lane * 2;
    int esel = lane >> 4, ek = lane & 15;
    const unsigned* __restrict__ XLu = (const unsigned*)XLh;
    float* ebA0 = &ebuf[wv][0][0];
    float* ebA1 = &ebuf[wv][1][0];
    float* ebB0 = &ebuf[wv][2][0];
    float* ebB1 = &ebuf[wv][3][0];

    f2 w2[16];
    #pragma unroll
    for (int k = 0; k < 16; ++k) w2[k] = *(const f2*)(We + k * DD + c);
    f2 att2 = *(const f2*)(att + c);
    f2 bg   = *(const f2*)(bias_gat + c);
    float w0 = weight1[0], w1v = weight1[1];
    float mw = fmaxf(w0, w1v);
    float e0w = __expf(w0 - mw), e1w = __expf(w1v - mw);
    float winv = 1.f / (e0w + e1w);
    float w1x = e0w * winv, w1a = e1w * winv;

    f2 bns = (f2)0.f, bnq = (f2)0.f;   // BN1 per-lane column stats

    for (int base = wid * 2; base < n; base += 2 * nwaves) {
        int iB = base + 1;
        bool hasB = iB < n;
        int iBe = base + 2 <= n ? base + 2 : n;
        int pA  = __builtin_amdgcn_readfirstlane(offsets[base]);
        int pm  = __builtin_amdgcn_readfirstlane(offsets[base + 1]);
        int pBe = __builtin_amdgcn_readfirstlane(offsets[iBe]);
        int cntA = pm - pA;                    // >= 1 (self-loop)
        int cntB = hasB ? pBe - pm : 0;
        int ngA = (cntA + 3) >> 2;
        int ngB = (cntB + 3) >> 2;
        int ng = ngA > ngB ? ngA : ngB;

        f2 xr2A = *(const f2*)(XR + (size_t)base * DD + c);
        f2 xr2B = hasB ? *(const f2*)(XR + (size_t)iB * DD + c) : (f2)0.f;

        float SA = 0.f, SB = 0.f;
        f2 axyA = (f2)0.f, axyB = (f2)0.f;

        unsigned a00, a01, a02, a03, a10, a11, a12, a13;
        unsigned b00, b01, b02, b03, b10, b11, b12, b13;
        float avA0, avA1, avB0, avB1;

        // prologue: group 0 of both streams
        GAT_LOAD4G(pA, pm, a00, a01, a02, a03, avA0);
        if (ngB > 0) GAT_LOAD4G(pm, pBe, b00, b01, b02, b03, avB0);
        ebA0[lane] = avA0;
        if (ngB > 0) ebB0[lane] = avB0;

        int t = 0;
        for (;;) {
            // even parity: compute buf0, prefetch buf1
            bool mA = (t + 1 < ngA), mB = (t + 1 < ngB);
            if (mA) GAT_LOAD4G(pA + 4 * (t + 1), pm, a10, a11, a12, a13, avA1);
            if (mB) GAT_LOAD4G(pm + 4 * (t + 1), pBe, b10, b11, b12, b13, avB1);
            if (t < ngA) GAT_COMPUTE4G(pA + 4 * t, pm, a00, a01, a02, a03, ebA0, SA, axyA, xr2A);
            if (mA) ebA1[lane] = avA1;         // write-late: vmcnt hidden by A compute
            if (t < ngB) GAT_COMPUTE4G(pm + 4 * t, pBe, b00, b01, b02, b03, ebB0, SB, axyB, xr2B);
            if (mB) ebB1[lane] = avB1;
            if (++t >= ng) break;
            // odd parity: compute buf1, prefetch buf0
            mA = (t + 1 < ngA); mB = (t + 1 < ngB);
            if (mA) GAT_LOAD4G(pA + 4 * (t + 1), pm, a00, a01, a02, a03, avA0);
            if (mB) GAT_LOAD4G(pm + 4 * (t + 1), pBe, b00, b01, b02, b03, avB0);
            if (t < ngA) GAT_COMPUTE4G(pA + 4 * t, pm, a10, a11, a12, a13, ebA1, SA, axyA, xr2A);
            if (mA) ebA0[lane] = avA0;
            if (t < ngB) GAT_COMPUTE4G(pm + 4 * t, pBe, b10, b11, b12, b13, ebB1, SB, axyB, xr2B);
            if (mB) ebB0[lane] = avB0;
            if (++t >= ng) break;
        }

        f2 xvA = *(const f2*)(x + (size_t)base * DD + c);
        f2 xvB = hasB ? *(const f2*)(x + (size_t)iB * DD + c) : (f2)0.f;

        float rlA = 1.f / SA;
        f2 avA = axyA * rlA + bg;
        f2 zvA = w1x * xvA + w1a * avA;
        *(f2*)(Z + (size_t)base * DD + c) = zvA;
        bns += zvA;
        bnq = __builtin_elementwise_fma(zvA, zvA, bnq);

        if (hasB) {
            float rlB = 1.f / SB;
            f2 avB = axyB * rlB + bg;
            f2 zvB = w1x * xvB + w1a * avB;
            *(f2*)(Z + (size_t)iB * DD + c) = zvB;
            bns += zvB;
            bnq = __builtin_elementwise_fma(zvB, zvB, bnq);
        }
    }

    // BN1 stats: block reduce (4 waves), then atomics into 32-way partial slots
    brs[wv][lane] = bns;
    brq[wv][lane] = bnq;
    __syncthreads();
    if (threadIdx.x < 64) {
        f2 s = brs[0][lane] + brs[1][lane] + brs[2][lane] + brs[3][lane];
        f2 q = brq[0][lane] + brq[1][lane] + brq[2][lane] + brq[3][lane];
        int bbase = (blockIdx.x & 31) * 128 + c;
        atomicAdd(&p1[bbase], s.x); atomicAdd(&p1[bbase + 1], s.y);
        atomicAdd(&q1[bbase], q.x); atomicAdd(&q1[bbase + 1], q.y);
    }
}

// nparts: number of 128-wide partial slots to reduce (32 for BN1, 1 for BN2)
__global__ __launch_bounds__(128) void k_bn_finish(const float* __restrict__ sums, const float* __restrict__ sumsq,
                                                   const float* __restrict__ gamma, const float* __restrict__ beta,
                                                   float* __restrict__ scale, float* __restrict__ shift,
                                                   int n, int nparts) {
    int t = threadIdx.x;
    if (t >= 128) return;
    float s = 0.f, q = 0.f;
    for (int pp = 0; pp < nparts; ++pp) {
        s += sums[pp * 128 + t];
        q += sumsq[pp * 128 + t];
    }
    float fn = (float)n;
    float mu = s / fn;
    float var = q / fn - mu * mu;
    float rstd = rsqrtf(var + EPSBN);
    float sc = gamma[t] * rstd;
    scale[t] = sc;
    shift[t] = fmaf(-mu, sc, beta[t]);
}

// ---------- conv1d(k=3) tiled GEMM: 64 rows x 128 co, 512 threads; fused BN2 stats ----------
// 64-row tiles (Bs traffic 153MB total) with 8 waves/block: 782 blocks x 8 waves ->
// ~24 waves/CU, LDS ~30KB. (32-row tiles regressed: doubled staging+barriers.)
__global__ __launch_bounds__(512) void k_conv(
    const float* __restrict__ Z, const float* __restrict__ scale1, const float* __restrict__ shift1,
    const float* __restrict__ wT, const float* __restrict__ conv_b,
    const float* __restrict__ weight2, float* __restrict__ Z2,
    float* __restrict__ sums2, float* __restrict__ sumsq2, int n)
{
    __shared__ float As[66 * 20];        // 5280 B
    __shared__ float Bs[3 * 16 * 128];   // 24576 B
    int tid = threadIdx.x;               // 0..511
    int r0 = blockIdx.x * 64;
    int tx = tid & 31, ty = tid >> 5;    // ty 0..15
    int rbase = ty * 4;

    float4 acc[4];
    #pragma unroll
    for (int j = 0; j < 4; ++j) acc[j] = make_float4(0.f, 0.f, 0.f, 0.f);

    for (int ci0 = 0; ci0 < 128; ci0 += 16) {
        // stage As: 66 rows x 16 ci = 264 float4, single pass over 512 threads
        if (tid < 264) {
            int lrow = tid >> 2, c4 = (tid & 3) * 4;
            int g = r0 - 1 + lrow;
            int cc = ci0 + c4;
            float4 v = make_float4(0.f, 0.f, 0.f, 0.f);
            if (g >= 0 && g < n) {
                float4 zv = *(const float4*)(Z + (size_t)g * DD + cc);
                const float4 s4v = *(const float4*)(scale1 + cc);
                const float4 h4v = *(const float4*)(shift1 + cc);
                v.x = fmaf(zv.x, s4v.x, h4v.x); v.y = fmaf(zv.y, s4v.y, h4v.y);
                v.z = fmaf(zv.z, s4v.z, h4v.z); v.w = fmaf(zv.w, s4v.w, h4v.w);
            }
            *(float4*)(As + lrow * 20 + c4) = v;
        }
        // stage Bs: 3 k x 16 ci x 128 co = 1536 float4 (3 per thread), coalesced
        #pragma unroll
        for (int s = 0; s < 3; ++s) {
            int idx = s * 512 + tid;
            int k = idx >> 9;            // /512
            int r = idx & 511;
            int ci = r >> 5, co4 = r & 31;
            ((float4*)Bs)[idx] = ((const float4*)wT)[(size_t)k * 4096 + (ci0 + ci) * 32 + co4];
        }
        __syncthreads();

        #pragma unroll 2
        for (int ci = 0; ci < 16; ++ci) {
            float a[6];
            #pragma unroll
            for (int j = 0; j < 6; ++j) a[j] = As[(rbase + j) * 20 + ci];
            float4 b0 = ((float4*)Bs)[(0 * 16 + ci) * 32 + tx];
            float4 b1 = ((float4*)Bs)[(1 * 16 + ci) * 32 + tx];
            float4 b2 = ((float4*)Bs)[(2 * 16 + ci) * 32 + tx];
            #pragma unroll
            for (int j = 0; j < 4; ++j) {
                acc[j] = f4_fma(a[j],     b0, acc[j]);
                acc[j] = f4_fma(a[j + 1], b1, acc[j]);
                acc[j] = f4_fma(a[j + 2], b2, acc[j]);
            }
        }
        __syncthreads();
    }

    float w0 = weight2[0], w1v = weight2[1];
    float mw = fmaxf(w0, w1v);
    float e0 = __expf(w0 - mw), e1 = __expf(w1v - mw);
    float winv = 1.f / (e0 + e1);
    float w2x = e0 * winv, w2a = e1 * winv;

    float4 cb = ((const float4*)conv_b)[tx];
    float4 sc1 = ((const float4*)scale1)[tx];
    float4 sh1 = ((const float4*)shift1)[tx];
    float4 s4 = make_float4(0.f, 0.f, 0.f, 0.f), q4 = s4;
    #pragma unroll
    for (int j = 0; j < 4; ++j) {
        int row = r0 + rbase + j;
        if (row >= n) break;
        float4 z1 = f4_add(acc[j], cb);
        z1.x = leakyf(z1.x, 0.01f); z1.y = leakyf(z1.y, 0.01f);
        z1.z = leakyf(z1.z, 0.01f); z1.w = leakyf(z1.w, 0.01f);
        float4 zv = ((const float4*)(Z + (size_t)row * DD))[tx];
        float4 zbn;
        zbn.x = fmaf(zv.x, sc1.x, sh1.x); zbn.y = fmaf(zv.y, sc1.y, sh1.y);
        zbn.z = fmaf(zv.z, sc1.z, sh1.z); zbn.w = fmaf(zv.w, sc1.w, sh1.w);
        float4 o;
        o.x = w2x * zbn.x + w2a * z1.x; o.y = w2x * zbn.y + w2a * z1.y;
        o.z = w2x * zbn.z + w2a * z1.z; o.w = w2x * zbn.w + w2a * z1.w;
        ((float4*)(Z2 + (size_t)row * DD))[tx] = o;
        s4 = f4_add(s4, o);
        q4.x = fmaf(o.x, o.x, q4.x); q4.y = fmaf(o.y, o.y, q4.y);
        q4.z = fmaf(o.z, o.z, q4.z); q4.w = fmaf(o.w, o.w, q4.w);
    }

    // fused BN2 stats: reduce over ty (16) in LDS (Bs dead: 1024 float4 = 16KB <= 24KB)
    float4* rs = (float4*)Bs;          // 512 float4
    float4* rq = rs + 512;             // 512 float4
    rs[ty * 32 + tx] = s4;
    rq[ty * 32 + tx] = q4;
    __syncthreads();
    if (tid < 32) {
        float4 ts = rs[tid], tq = rq[tid];
        #pragma unroll
        for (int j = 1; j < 16; ++j) { ts = f4_add(ts, rs[j * 32 + tid]); tq = f4_add(tq, rq[j * 32 + tid]); }
        atomicAdd(&sums2[tid * 4 + 0], ts.x); atomicAdd(&sums2[tid * 4 + 1], ts.y);
        atomicAdd(&sums2[tid * 4 + 2], ts.z); atomicAdd(&sums2[tid * 4 + 3], ts.w);
        atomicAdd(&sumsq2[tid * 4 + 0], tq.x); atomicAdd(&sumsq2[tid * 4 + 1], tq.y);
        atomicAdd(&sumsq2[tid * 4 + 2], tq.z); atomicAdd(&sumsq2[tid * 4 + 3], tq.w);
    }
}

// ---------- final BN2 apply ----------
__global__ __launch_bounds__(256) void k_final(const float* __restrict__ Z2,
                                               const float* __restrict__ scale2, const float* __restrict__ shift2,
                                               float* __restrict__ out, int total4) {
    int idx = blockIdx.x * 256 + threadIdx.x;
    if (idx >= total4) return;
    int c4 = idx & 31;
    float4 v = ((const float4*)Z2)[idx];
    float4 sc = ((const float4*)scale2)[c4];
    float4 sh = ((const float4*)shift2)[c4];
    float4 r;
    r.x = fmaf(v.x, sc.x, sh.x); r.y = fmaf(v.y, sc.y, sh.y);
    r.z = fmaf(v.z, sc.z, sh.z); r.w = fmaf(v.w, sc.w, sh.w);
    ((float4*)out)[idx] = r;
}

extern "C" void kernel_launch(void* const* d_in, const int* in_sizes, int n_in,
                              void* d_out, int out_size, void* d_ws, size_t ws_size,
                              hipStream_t stream)
{
    const float* x          = (const float*)d_in[0];
    const int*   edge_index = (const int*)d_in[1];
    const float* edge_attr  = (const float*)d_in[2];
    const float* W_l        = (const float*)d_in[3];
    const float* b_l        = (const float*)d_in[4];
    const float* W_r        = (const float*)d_in[5];
    const float* b_r        = (const float*)d_in[6];
    const float* W_e        = (const float*)d_in[7];
    const float* att        = (const float*)d_in[8];
    const float* bias_gat   = (const float*)d_in[9];
    const float* weight1    = (const float*)d_in[10];
    const float* bn1_gamma  = (const float*)d_in[11];
    const float* bn1_beta   = (const float*)d_in[12];
    const float* conv_w     = (const float*)d_in[13];
    const float* conv_b     = (const float*)d_in[14];
    const float* weight2    = (const float*)d_in[15];
    const float* bn2_gamma  = (const float*)d_in[16];
    const float* bn2_beta   = (const float*)d_in[17];

    int n = in_sizes[0] / DD;   // 50000
    int e = in_sizes[1] / 2;    // 800000
    int nchunks = (n + 255) / 256;

    float* XR = (float*)d_ws;                 // n*128 f32
    float* Z  = XR + (size_t)n * DD;          // n*128 f32
    float* wT = Z + (size_t)n * DD;           // 3*128*128
    float* stats = wT + 49152;                // 1024 + 8192 floats (zeroed in k_prep)
    float* sums2 = stats + 256, *sumsq2 = stats + 384;
    float* scale1 = stats + 512, *shift1 = stats + 640;
    float* scale2 = stats + 768, *shift2 = stats + 896;
    float* p1 = stats + 1024;                 // [32][128] BN1 sum partials
    float* q1 = p1 + 4096;                    // [32][128] BN1 sumsq partials
    int* counts  = (int*)(q1 + 4096);         // n
    int* offsets = counts + n;                // n+2 (even pad)
    int* cursor  = offsets + n + 2;           // n
    int* bsum    = cursor + n;                // nchunks+1, round to even
    int2* epair  = (int2*)(bsum + ((nchunks + 2) & ~1));  // e+n pairs (eid|-1, src)
    unsigned short* XLh = (unsigned short*)(epair + e + n);  // n*128 bf16
    float* Z2 = XR;                           // alias: XR dead after k_gat

    const int* src = edge_index;
    const int* dst = edge_index + e;

    const int nwaves = 8192;  // 2048 blocks x 4 waves
    const int nstats = 1024 + 8192;

    k_prep<<<(3 * 128 * 128 + n + nstats + 255) / 256, 256, 0, stream>>>(conv_w, wT, counts, stats, n, nstats);
    k_gemm_xlxr<<<(n + 63) / 64, 256, 0, stream>>>(x, W_l, b_l, W_r, b_r, XR, XLh, n);
    k_hist<<<(e + 255) / 256, 256, 0, stream>>>(dst, counts, e);
    k_scan1<<<nchunks, 256, 0, stream>>>(counts, offsets, bsum, n);
    k_scan2<<<1, 1024, 0, stream>>>(bsum, nchunks);
    k_scan3<<<(n + 256) / 256, 256, 0, stream>>>(offsets, cursor, bsum, epair, n, nchunks);
    k_scatter<<<(e + 255) / 256, 256, 0, stream>>>(src, dst, cursor, epair, e);
    k_gat<<<nwaves / 4, 256, 0, stream>>>(XLh, XR, x, epair, offsets,
                                          edge_attr, W_e, att, bias_gat, weight1, Z,
                                          p1, q1, n, nwaves);
    k_bn_finish<<<1, 128, 0, stream>>>(p1, q1, bn1_gamma, bn1_beta, scale1, shift1, n, 32);
    k_conv<<<(n + 63) / 64, 512, 0, stream>>>(Z, scale1, shift1, wT, conv_b, weight2, Z2,
                                              sums2, sumsq2, n);
    k_bn_finish<<<1, 128, 0, stream>>>(sums2, sumsq2, bn2_gamma, bn2_beta, scale2, shift2, n, 1);
    k_final<<<(n * 32 + 255) / 256, 256, 0, stream>>>(Z2, scale2, shift2, (float*)d_out, n * 32);
}

// Round 12
// 560.714 us; speedup vs baseline: 1.1032x; 1.1032x over previous
//
#include <hip/hip_runtime.h>
#include <hip/hip_bf16.h>
#include <math.h>

#define DD 128
#define EPSBN 1e-5f

typedef float f2 __attribute__((ext_vector_type(2)));

// ---------- small helpers ----------
__device__ __forceinline__ float4 f4_add(float4 a, float4 b) {
    return make_float4(a.x + b.x, a.y + b.y, a.z + b.z, a.w + b.w);
}
__device__ __forceinline__ float4 f4_fma(float a, float4 b, float4 c) {
    c.x = fmaf(a, b.x, c.x); c.y = fmaf(a, b.y, c.y);
    c.z = fmaf(a, b.z, c.z); c.w = fmaf(a, b.w, c.w);
    return c;
}
__device__ __forceinline__ float leakyf(float v, float s) { return v > 0.f ? v : s * v; }

__device__ __forceinline__ unsigned short f2bf(float f) {   // RNE
    unsigned u = __float_as_uint(f);
    return (unsigned short)((u + 0x7fffu + ((u >> 16) & 1u)) >> 16);
}
__device__ __forceinline__ f2 bfu2f2(unsigned u) {          // packed 2×bf16 -> 2×f32
    f2 r;
    r.x = __uint_as_float(u << 16);
    r.y = __uint_as_float(u & 0xFFFF0000u);
    return r;
}
__device__ __forceinline__ f2 leaky2(f2 v, float s) {
    f2 z = (f2)0.f;
    return __builtin_elementwise_max(v, z) + s * __builtin_elementwise_min(v, z);
}

// ---------- prep: transpose conv_w AND zero counts/stats(+BN1 partials) ----------
__global__ __launch_bounds__(256) void k_prep(const float* __restrict__ conv_w, float* __restrict__ wT,
                                              int* __restrict__ counts, float* __restrict__ stats,
                                              int n, int nstats) {
    int idx = blockIdx.x * 256 + threadIdx.x;
    if (idx < 3 * 128 * 128) {
        int k = idx >> 14;
        int r = idx & 16383;
        int ci = r >> 7, co = r & 127;
        wT[idx] = conv_w[(size_t)co * 384 + ci * 3 + k];
    }
    int z = idx - 3 * 128 * 128;
    if (z >= 0) {
        if (z < n) counts[z] = 0;
        else if (z - n < nstats) stats[z - n] = 0.f;
    }
}

// ---------- XR = x@W_r + b_r (fp32); XLh = bf16(x@W_l + b_l) ----------
__global__ __launch_bounds__(256) void k_gemm_xlxr(
    const float* __restrict__ x, const float* __restrict__ Wl, const float* __restrict__ bl,
    const float* __restrict__ Wr, const float* __restrict__ br,
    float* __restrict__ XR, unsigned short* __restrict__ XLh, int n)
{
    __shared__ float As[64 * 33];
    __shared__ float Bs[32 * 256];
    int tid = threadIdx.x;
    int r0 = blockIdx.x * 64;
    int tx = tid & 31, ty = tid >> 5;

    float4 accL[8], accR[8];
    #pragma unroll
    for (int j = 0; j < 8; ++j) {
        accL[j] = make_float4(0.f, 0.f, 0.f, 0.f);
        accR[j] = make_float4(0.f, 0.f, 0.f, 0.f);
    }

    for (int k0 = 0; k0 < 128; k0 += 32) {
        for (int idx = tid; idx < 64 * 32; idx += 256) {
            int lrow = idx >> 5, kk = idx & 31;
            int g = r0 + lrow;
            As[lrow * 33 + kk] = (g < n) ? x[(size_t)g * DD + k0 + kk] : 0.f;
        }
        for (int idx = tid; idx < 2048; idx += 256) {
            int kk = idx >> 6, co4 = idx & 63;
            float4 v;
            if (co4 < 32) v = ((const float4*)Wl)[(size_t)(k0 + kk) * 32 + co4];
            else          v = ((const float4*)Wr)[(size_t)(k0 + kk) * 32 + (co4 - 32)];
            ((float4*)Bs)[kk * 64 + co4] = v;
        }
        __syncthreads();

        #pragma unroll 4
        for (int kk = 0; kk < 32; ++kk) {
            float a[8];
            #pragma unroll
            for (int j = 0; j < 8; ++j) a[j] = As[(ty * 8 + j) * 33 + kk];
            float4 bL = ((float4*)Bs)[kk * 64 + tx];
            float4 bR = ((float4*)Bs)[kk * 64 + 32 + tx];
            #pragma unroll
            for (int j = 0; j < 8; ++j) {
                accL[j] = f4_fma(a[j], bL, accL[j]);
                accR[j] = f4_fma(a[j], bR, accR[j]);
            }
        }
        __syncthreads();
    }

    float4 blv = ((const float4*)bl)[tx];
    float4 brv = ((const float4*)br)[tx];
    #pragma unroll
    for (int j = 0; j < 8; ++j) {
        int row = r0 + ty * 8 + j;
        if (row < n) {
            float4 L4 = f4_add(accL[j], blv);
            ((float4*)(XR + (size_t)row * DD))[tx] = f4_add(accR[j], brv);
            uint2 hp;
            hp.x = (unsigned)f2bf(L4.x) | ((unsigned)f2bf(L4.y) << 16);
            hp.y = (unsigned)f2bf(L4.z) | ((unsigned)f2bf(L4.w) << 16);
            ((uint2*)(XLh + (size_t)row * DD))[tx] = hp;
        }
    }
}

// ---------- CSR build ----------
__global__ __launch_bounds__(256) void k_hist(const int* __restrict__ dst, int* __restrict__ counts, int e) {
    int idx = blockIdx.x * 256 + threadIdx.x;
    if (idx < e) atomicAdd(&counts[dst[idx]], 1);
}

// 3-stage parallel scan: chunk-local scan -> chunk-sum scan -> add-back
__global__ __launch_bounds__(256) void k_scan1(const int* __restrict__ counts,
                                               int* __restrict__ offsets, int* __restrict__ bsum, int n) {
    __shared__ int tmp[256];
    int t = threadIdx.x;
    int i = blockIdx.x * 256 + t;
    int v = (i < n) ? counts[i] : 0;
    tmp[t] = v;
    __syncthreads();
    for (int off = 1; off < 256; off <<= 1) {
        int u = (t >= off) ? tmp[t - off] : 0;
        __syncthreads();
        tmp[t] += u;
        __syncthreads();
    }
    if (i < n) offsets[i] = tmp[t] - v;          // exclusive within chunk
    if (t == 255) bsum[blockIdx.x] = tmp[255];   // chunk total
}

__global__ __launch_bounds__(1024) void k_scan2(int* __restrict__ bsum, int nchunks) {
    __shared__ int tmp[1024];
    int t = threadIdx.x;
    int v = (t < nchunks) ? bsum[t] : 0;
    tmp[t] = v;
    __syncthreads();
    for (int off = 1; off < 1024; off <<= 1) {
        int u = (t >= off) ? tmp[t - off] : 0;
        __syncthreads();
        tmp[t] += u;
        __syncthreads();
    }
    if (t < nchunks) bsum[t] = tmp[t] - v;       // exclusive chunk prefix
    if (t == 0) bsum[nchunks] = tmp[nchunks - 1]; // grand total
}

__global__ __launch_bounds__(256) void k_scan3(int* __restrict__ offsets, int* __restrict__ cursor,
                                               const int* __restrict__ bsum, int n, int nchunks) {
    int i = blockIdx.x * 256 + threadIdx.x;
    if (i < n) {
        int o = offsets[i] + bsum[i >> 8];
        offsets[i] = o;
        cursor[i] = o;
    }
    if (i == n) offsets[n] = bsum[nchunks];
}

__global__ __launch_bounds__(256) void k_scatter(const int* __restrict__ src, const int* __restrict__ dst,
                                                 int* __restrict__ cursor, int2* __restrict__ epair, int e) {
    int idx = blockIdx.x * 256 + threadIdx.x;
    if (idx >= e) return;
    int d = dst[idx];
    int pos = atomicAdd(&cursor[d], 1);
    epair[pos] = make_int2(idx, src[idx]);
}

// ---------- fused GATv2: wave-per-node (grid-strided), no-max softmax, single gather pass ----------
// exp(l) without max subtraction is safe: logit sigma ~1.5, max over 850k edges ~8 << 88.
// R19: depth-1 caps per-iteration time at max(compute, gather-latency) ~ latency (VALU 48%).
// R13's depth-2 collapsed because attr was the LAST load in a group: the eb write's vmcnt
// wait drained the whole group's gathers. Fix: attr load issued FIRST -> eb write waits only
// attr (early), gathers of groups t+1/t+2 stay in flight -> group t's gathers get TWO
// compute phases (~520cy) of cover. 3-buffer A/B/C rotation, static indices, serial tail.
// (R18's dual-stream also regressed: max(ngA,ngB) imbalance + occupancy drop. Reverted.)

#define EPROJ(EB_, J_, EV_) {                                                   \
    const float4* e4_ = ((const float4*)(EB_)) + (J_) * 4;                      \
    float4 a0_ = e4_[0], a1_ = e4_[1], a2_ = e4_[2], a3_ = e4_[3];              \
    f2 v_ = (f2)0.f;                                                            \
    v_ = __builtin_elementwise_fma((f2)a0_.x, w2[0],  v_);                      \
    v_ = __builtin_elementwise_fma((f2)a0_.y, w2[1],  v_);                      \
    v_ = __builtin_elementwise_fma((f2)a0_.z, w2[2],  v_);                      \
    v_ = __builtin_elementwise_fma((f2)a0_.w, w2[3],  v_);                      \
    v_ = __builtin_elementwise_fma((f2)a1_.x, w2[4],  v_);                      \
    v_ = __builtin_elementwise_fma((f2)a1_.y, w2[5],  v_);                      \
    v_ = __builtin_elementwise_fma((f2)a1_.z, w2[6],  v_);                      \
    v_ = __builtin_elementwise_fma((f2)a1_.w, w2[7],  v_);                      \
    v_ = __builtin_elementwise_fma((f2)a2_.x, w2[8],  v_);                      \
    v_ = __builtin_elementwise_fma((f2)a2_.y, w2[9],  v_);                      \
    v_ = __builtin_elementwise_fma((f2)a2_.z, w2[10], v_);                      \
    v_ = __builtin_elementwise_fma((f2)a2_.w, w2[11], v_);                      \
    v_ = __builtin_elementwise_fma((f2)a3_.x, w2[12], v_);                      \
    v_ = __builtin_elementwise_fma((f2)a3_.y, w2[13], v_);                      \
    v_ = __builtin_elementwise_fma((f2)a3_.z, w2[14], v_);                      \
    v_ = __builtin_elementwise_fma((f2)a3_.w, w2[15], v_);                      \
    EV_ = v_; }

// attr load issued FIRST so a later wait-for-attr keeps the 4 gathers in flight
#define GAT_LOAD4(q_, U0_, U1_, U2_, U3_, AV_) {                                \
    int2 g0_ = epair[q_], g1_ = epair[(q_) + 1];                                \
    int2 g2_ = epair[(q_) + 2], g3_ = epair[(q_) + 3];                          \
    int ej_ = esel == 0 ? g0_.x : esel == 1 ? g1_.x : esel == 2 ? g2_.x : g3_.x;\
    AV_ = edge_attr[(size_t)ej_ * 16 + ek];                                     \
    int s0_ = __builtin_amdgcn_readfirstlane(g0_.y);                            \
    int s1_ = __builtin_amdgcn_readfirstlane(g1_.y);                            \
    int s2_ = __builtin_amdgcn_readfirstlane(g2_.y);                            \
    int s3_ = __builtin_amdgcn_readfirstlane(g3_.y);                            \
    U0_ = XLu[(size_t)s0_ * 64 + lane];                                         \
    U1_ = XLu[(size_t)s1_ * 64 + lane];                                         \
    U2_ = XLu[(size_t)s2_ * 64 + lane];                                         \
    U3_ = XLu[(size_t)s3_ * 64 + lane]; }

#define GAT_COMPUTE4(U0_, U1_, U2_, U3_, EB_) {                                 \
    f2 x0_ = bfu2f2(U0_), x1_ = bfu2f2(U1_);                                    \
    f2 x2_ = bfu2f2(U2_), x3_ = bfu2f2(U3_);                                    \
    f2 ev0_, ev1_, ev2_, ev3_;                                                  \
    EPROJ(EB_, 0, ev0_); EPROJ(EB_, 1, ev1_);                                   \
    EPROJ(EB_, 2, ev2_); EPROJ(EB_, 3, ev3_);                                   \
    f2 m0_ = leaky2(x0_ + xr2 + ev0_, 0.2f);                                    \
    f2 m1_ = leaky2(x1_ + xr2 + ev1_, 0.2f);                                    \
    f2 m2_ = leaky2(x2_ + xr2 + ev2_, 0.2f);                                    \
    f2 m3_ = leaky2(x3_ + xr2 + ev3_, 0.2f);                                    \
    float l0_ = m0_.x * att2.x + m0_.y * att2.y;                                \
    float l1_ = m1_.x * att2.x + m1_.y * att2.y;                                \
    float l2_ = m2_.x * att2.x + m2_.y * att2.y;                                \
    float l3_ = m3_.x * att2.x + m3_.y * att2.y;                                \
    _Pragma("unroll")                                                           \
    for (int off_ = 32; off_ > 0; off_ >>= 1) {                                 \
        l0_ += __shfl_xor(l0_, off_, 64);                                       \
        l1_ += __shfl_xor(l1_, off_, 64);                                       \
        l2_ += __shfl_xor(l2_, off_, 64);                                       \
        l3_ += __shfl_xor(l3_, off_, 64);                                       \
    }                                                                           \
    float g0_ = __expf(l0_), g1_ = __expf(l1_);                                 \
    float g2_ = __expf(l2_), g3_ = __expf(l3_);                                 \
    S += (g0_ + g1_) + (g2_ + g3_);                                             \
    axy = __builtin_elementwise_fma((f2)g0_, x0_, axy);                         \
    axy = __builtin_elementwise_fma((f2)g1_, x1_, axy);                         \
    axy = __builtin_elementwise_fma((f2)g2_, x2_, axy);                         \
    axy = __builtin_elementwise_fma((f2)g3_, x3_, axy); }

__global__ __launch_bounds__(256) void k_gat(
    const unsigned short* __restrict__ XLh, const float* __restrict__ XR,
    const float* __restrict__ x,
    const int2* __restrict__ epair, const int* __restrict__ offsets,
    const float* __restrict__ edge_attr, const float* __restrict__ We,
    const float* __restrict__ att, const float* __restrict__ bias_gat,
    const float* __restrict__ weight1, float* __restrict__ Z,
    float* __restrict__ p1, float* __restrict__ q1, int n, int nwaves)
{
    __shared__ float ebuf[4][3][64];   // [wave][buf][4 edges * 16 attrs]
    __shared__ f2 brs[4][64];          // BN1 stats block reduce
    __shared__ f2 brq[4][64];
    int wv   = threadIdx.x >> 6;
    int wid  = blockIdx.x * 4 + wv;
    int lane = threadIdx.x & 63;
    int c = lane * 2;
    int esel = lane >> 4, ek = lane & 15;
    const unsigned* __restrict__ XLu = (const unsigned*)XLh;
    float* ebA = &ebuf[wv][0][0];
    float* ebB = &ebuf[wv][1][0];
    float* ebC = &ebuf[wv][2][0];

    f2 w2[16];
    #pragma unroll
    for (int k = 0; k < 16; ++k) w2[k] = *(const f2*)(We + k * DD + c);
    f2 att2 = *(const f2*)(att + c);
    f2 bg   = *(const f2*)(bias_gat + c);
    float w0 = weight1[0], w1v = weight1[1];
    float mw = fmaxf(w0, w1v);
    float e0w = __expf(w0 - mw), e1w = __expf(w1v - mw);
    float winv = 1.f / (e0w + e1w);
    float w1x = e0w * winv, w1a = e1w * winv;

    f2 bns = (f2)0.f, bnq = (f2)0.f;   // BN1 per-lane column stats

    for (int i = wid; i < n; i += nwaves) {
        f2 xr2 = *(const f2*)(XR + (size_t)i * DD + c);
        f2 xli = bfu2f2(XLu[(size_t)i * 64 + lane]);

        // self loop (e contribution is 0)
        f2 ms = leaky2(xli + xr2, 0.2f);
        float sl = ms.x * att2.x + ms.y * att2.y;
        #pragma unroll
        for (int off = 32; off > 0; off >>= 1) sl += __shfl_xor(sl, off, 64);
        float gs = __expf(sl);
        float S = gs;
        f2 axy = gs * xli;

        int p  = __builtin_amdgcn_readfirstlane(offsets[i]);
        int pe = __builtin_amdgcn_readfirstlane(offsets[i + 1]);
        int cnt = pe - p;
        int ng = cnt >> 2;

        if (ng > 0) {
            unsigned uA0, uA1, uA2, uA3, uB0, uB1, uB2, uB3, uC0, uC1, uC2, uC3;
            float avA, avB, avC;
            GAT_LOAD4(p, uA0, uA1, uA2, uA3, avA);
            ebA[lane] = avA;                         // prologue stage
            if (ng > 1) GAT_LOAD4(p + 4, uB0, uB1, uB2, uB3, avB);
            int t = 0;
            for (;;) {
                if (t + 2 < ng) GAT_LOAD4(p + 4 * (t + 2), uC0, uC1, uC2, uC3, avC);
                if (t + 1 < ng) ebB[lane] = avB;     // waits attr only (attr-first)
                GAT_COMPUTE4(uA0, uA1, uA2, uA3, ebA);
                if (++t >= ng) break;
                if (t + 2 < ng) GAT_LOAD4(p + 4 * (t + 2), uA0, uA1, uA2, uA3, avA);
                if (t + 1 < ng) ebC[lane] = avC;
                GAT_COMPUTE4(uB0, uB1, uB2, uB3, ebB);
                if (++t >= ng) break;
                if (t + 2 < ng) GAT_LOAD4(p + 4 * (t + 2), uB0, uB1, uB2, uB3, avB);
                if (t + 1 < ng) ebA[lane] = avA;
                GAT_COMPUTE4(uC0, uC1, uC2, uC3, ebC);
                if (++t >= ng) break;
            }
        }
        for (int q = p + (ng << 2); q < pe; ++q) {   // tail 0-3 edges
            int2 ej = epair[q];
            int eid = __builtin_amdgcn_readfirstlane(ej.x);
            int srn = __builtin_amdgcn_readfirstlane(ej.y);
            unsigned u = XLu[(size_t)srn * 64 + lane];
            const float* pa = edge_attr + (size_t)eid * 16;
            f2 ev = (f2)0.f;
            #pragma unroll
            for (int k = 0; k < 16; ++k) ev = __builtin_elementwise_fma((f2)pa[k], w2[k], ev);
            f2 x0 = bfu2f2(u);
            f2 m = leaky2(x0 + xr2 + ev, 0.2f);
            float l = m.x * att2.x + m.y * att2.y;
            #pragma unroll
            for (int off = 32; off > 0; off >>= 1) l += __shfl_xor(l, off, 64);
            float g = __expf(l);
            S += g;
            axy = __builtin_elementwise_fma((f2)g, x0, axy);
        }

        float rl = 1.f / S;
        f2 av = axy * rl + bg;
        f2 xv = *(const f2*)(x + (size_t)i * DD + c);
        f2 zv = w1x * xv + w1a * av;
        *(f2*)(Z + (size_t)i * DD + c) = zv;
        bns += zv;
        bnq = __builtin_elementwise_fma(zv, zv, bnq);
    }

    // BN1 stats: block reduce (4 waves), then atomics into 32-way partial slots
    brs[wv][lane] = bns;
    brq[wv][lane] = bnq;
    __syncthreads();
    if (threadIdx.x < 64) {
        f2 s = brs[0][lane] + brs[1][lane] + brs[2][lane] + brs[3][lane];
        f2 q = brq[0][lane] + brq[1][lane] + brq[2][lane] + brq[3][lane];
        int bbase = (blockIdx.x & 31) * 128 + c;
        atomicAdd(&p1[bbase], s.x); atomicAdd(&p1[bbase + 1], s.y);
        atomicAdd(&q1[bbase], q.x); atomicAdd(&q1[bbase + 1], q.y);
    }
}

// nparts: number of 128-wide partial slots to reduce (32 for BN1, 1 for BN2)
__global__ __launch_bounds__(128) void k_bn_finish(const float* __restrict__ sums, const float* __restrict__ sumsq,
                                                   const float* __restrict__ gamma, const float* __restrict__ beta,
                                                   float* __restrict__ scale, float* __restrict__ shift,
                                                   int n, int nparts) {
    int t = threadIdx.x;
    if (t >= 128) return;
    float s = 0.f, q = 0.f;
    for (int pp = 0; pp < nparts; ++pp) {
        s += sums[pp * 128 + t];
        q += sumsq[pp * 128 + t];
    }
    float fn = (float)n;
    float mu = s / fn;
    float var = q / fn - mu * mu;
    float rstd = rsqrtf(var + EPSBN);
    float sc = gamma[t] * rstd;
    scale[t] = sc;
    shift[t] = fmaf(-mu, sc, beta[t]);
}

// ---------- conv1d(k=3) tiled GEMM: 64 rows x 128 co, 512 threads; fused BN2 stats ----------
// 64-row tiles (Bs traffic 153MB total) with 8 waves/block: 782 blocks x 8 waves ->
// ~24 waves/CU, LDS ~30KB. (32-row tiles regressed: doubled staging+barriers.)
__global__ __launch_bounds__(512) void k_conv(
    const float* __restrict__ Z, const float* __restrict__ scale1, const float* __restrict__ shift1,
    const float* __restrict__ wT, const float* __restrict__ conv_b,
    const float* __restrict__ weight2, float* __restrict__ Z2,
    float* __restrict__ sums2, float* __restrict__ sumsq2, int n)
{
    __shared__ float As[66 * 20];        // 5280 B
    __shared__ float Bs[3 * 16 * 128];   // 24576 B
    int tid = threadIdx.x;               // 0..511
    int r0 = blockIdx.x * 64;
    int tx = tid & 31, ty = tid >> 5;    // ty 0..15
    int rbase = ty * 4;

    float4 acc[4];
    #pragma unroll
    for (int j = 0; j < 4; ++j) acc[j] = make_float4(0.f, 0.f, 0.f, 0.f);

    for (int ci0 = 0; ci0 < 128; ci0 += 16) {
        // stage As: 66 rows x 16 ci = 264 float4, single pass over 512 threads
        if (tid < 264) {
            int lrow = tid >> 2, c4 = (tid & 3) * 4;
            int g = r0 - 1 + lrow;
            int cc = ci0 + c4;
            float4 v = make_float4(0.f, 0.f, 0.f, 0.f);
            if (g >= 0 && g < n) {
                float4 zv = *(const float4*)(Z + (size_t)g * DD + cc);
                const float4 s4v = *(const float4*)(scale1 + cc);
                const float4 h4v = *(const float4*)(shift1 + cc);
                v.x = fmaf(zv.x, s4v.x, h4v.x); v.y = fmaf(zv.y, s4v.y, h4v.y);
                v.z = fmaf(zv.z, s4v.z, h4v.z); v.w = fmaf(zv.w, s4v.w, h4v.w);
            }
            *(float4*)(As + lrow * 20 + c4) = v;
        }
        // stage Bs: 3 k x 16 ci x 128 co = 1536 float4 (3 per thread), coalesced
        #pragma unroll
        for (int s = 0; s < 3; ++s) {
            int idx = s * 512 + tid;
            int k = idx >> 9;            // /512
            int r = idx & 511;
            int ci = r >> 5, co4 = r & 31;
            ((float4*)Bs)[idx] = ((const float4*)wT)[(size_t)k * 4096 + (ci0 + ci) * 32 + co4];
        }
        __syncthreads();

        #pragma unroll 2
        for (int ci = 0; ci < 16; ++ci) {
            float a[6];
            #pragma unroll
            for (int j = 0; j < 6; ++j) a[j] = As[(rbase + j) * 20 + ci];
            float4 b0 = ((float4*)Bs)[(0 * 16 + ci) * 32 + tx];
            float4 b1 = ((float4*)Bs)[(1 * 16 + ci) * 32 + tx];
            float4 b2 = ((float4*)Bs)[(2 * 16 + ci) * 32 + tx];
            #pragma unroll
            for (int j = 0; j < 4; ++j) {
                acc[j] = f4_fma(a[j],     b0, acc[j]);
                acc[j] = f4_fma(a[j + 1], b1, acc[j]);
                acc[j] = f4_fma(a[j + 2], b2, acc[j]);
            }
        }
        __syncthreads();
    }

    float w0 = weight2[0], w1v = weight2[1];
    float mw = fmaxf(w0, w1v);
    float e0 = __expf(w0 - mw), e1 = __expf(w1v - mw);
    float winv = 1.f / (e0 + e1);
    float w2x = e0 * winv, w2a = e1 * winv;

    float4 cb = ((const float4*)conv_b)[tx];
    float4 sc1 = ((const float4*)scale1)[tx];
    float4 sh1 = ((const float4*)shift1)[tx];
    float4 s4 = make_float4(0.f, 0.f, 0.f, 0.f), q4 = s4;
    #pragma unroll
    for (int j = 0; j < 4; ++j) {
        int row = r0 + rbase + j;
        if (row >= n) break;
        float4 z1 = f4_add(acc[j], cb);
        z1.x = leakyf(z1.x, 0.01f); z1.y = leakyf(z1.y, 0.01f);
        z1.z = leakyf(z1.z, 0.01f); z1.w = leakyf(z1.w, 0.01f);
        float4 zv = ((const float4*)(Z + (size_t)row * DD))[tx];
        float4 zbn;
        zbn.x = fmaf(zv.x, sc1.x, sh1.x); zbn.y = fmaf(zv.y, sc1.y, sh1.y);
        zbn.z = fmaf(zv.z, sc1.z, sh1.z); zbn.w = fmaf(zv.w, sc1.w, sh1.w);
        float4 o;
        o.x = w2x * zbn.x + w2a * z1.x; o.y = w2x * zbn.y + w2a * z1.y;
        o.z = w2x * zbn.z + w2a * z1.z; o.w = w2x * zbn.w + w2a * z1.w;
        ((float4*)(Z2 + (size_t)row * DD))[tx] = o;
        s4 = f4_add(s4, o);
        q4.x = fmaf(o.x, o.x, q4.x); q4.y = fmaf(o.y, o.y, q4.y);
        q4.z = fmaf(o.z, o.z, q4.z); q4.w = fmaf(o.w, o.w, q4.w);
    }

    // fused BN2 stats: reduce over ty (16) in LDS (Bs dead: 1024 float4 = 16KB <= 24KB)
    float4* rs = (float4*)Bs;          // 512 float4
    float4* rq = rs + 512;             // 512 float4
    rs[ty * 32 + tx] = s4;
    rq[ty * 32 + tx] = q4;
    __syncthreads();
    if (tid < 32) {
        float4 ts = rs[tid], tq = rq[tid];
        #pragma unroll
        for (int j = 1; j < 16; ++j) { ts = f4_add(ts, rs[j * 32 + tid]); tq = f4_add(tq, rq[j * 32 + tid]); }
        atomicAdd(&sums2[tid * 4 + 0], ts.x); atomicAdd(&sums2[tid * 4 + 1], ts.y);
        atomicAdd(&sums2[tid * 4 + 2], ts.z); atomicAdd(&sums2[tid * 4 + 3], ts.w);
        atomicAdd(&sumsq2[tid * 4 + 0], tq.x); atomicAdd(&sumsq2[tid * 4 + 1], tq.y);
        atomicAdd(&sumsq2[tid * 4 + 2], tq.z); atomicAdd(&sumsq2[tid * 4 + 3], tq.w);
    }
}

// ---------- final BN2 apply ----------
__global__ __launch_bounds__(256) void k_final(const float* __restrict__ Z2,
                                               const float* __restrict__ scale2, const float* __restrict__ shift2,
                                               float* __restrict__ out, int total4) {
    int idx = blockIdx.x * 256 + threadIdx.x;
    if (idx >= total4) return;
    int c4 = idx & 31;
    float4 v = ((const float4*)Z2)[idx];
    float4 sc = ((const float4*)scale2)[c4];
    float4 sh = ((const float4*)shift2)[c4];
    float4 r;
    r.x = fmaf(v.x, sc.x, sh.x); r.y = fmaf(v.y, sc.y, sh.y);
    r.z = fmaf(v.z, sc.z, sh.z); r.w = fmaf(v.w, sc.w, sh.w);
    ((float4*)out)[idx] = r;
}

extern "C" void kernel_launch(void* const* d_in, const int* in_sizes, int n_in,
                              void* d_out, int out_size, void* d_ws, size_t ws_size,
                              hipStream_t stream)
{
    const float* x          = (const float*)d_in[0];
    const int*   edge_index = (const int*)d_in[1];
    const float* edge_attr  = (const float*)d_in[2];
    const float* W_l        = (const float*)d_in[3];
    const float* b_l        = (const float*)d_in[4];
    const float* W_r        = (const float*)d_in[5];
    const float* b_r        = (const float*)d_in[6];
    const float* W_e        = (const float*)d_in[7];
    const float* att        = (const float*)d_in[8];
    const float* bias_gat   = (const float*)d_in[9];
    const float* weight1    = (const float*)d_in[10];
    const float* bn1_gamma  = (const float*)d_in[11];
    const float* bn1_beta   = (const float*)d_in[12];
    const float* conv_w     = (const float*)d_in[13];
    const float* conv_b     = (const float*)d_in[14];
    const float* weight2    = (const float*)d_in[15];
    const float* bn2_gamma  = (const float*)d_in[16];
    const float* bn2_beta   = (const float*)d_in[17];

    int n = in_sizes[0] / DD;   // 50000
    int e = in_sizes[1] / 2;    // 800000
    int nchunks = (n + 255) / 256;

    float* XR = (float*)d_ws;                 // n*128 f32
    float* Z  = XR + (size_t)n * DD;          // n*128 f32
    float* wT = Z + (size_t)n * DD;           // 3*128*128
    float* stats = wT + 49152;                // 1024 + 8192 floats (zeroed in k_prep)
    float* sums2 = stats + 256, *sumsq2 = stats + 384;
    float* scale1 = stats + 512, *shift1 = stats + 640;
    float* scale2 = stats + 768, *shift2 = stats + 896;
    float* p1 = stats + 1024;                 // [32][128] BN1 sum partials
    float* q1 = p1 + 4096;                    // [32][128] BN1 sumsq partials
    int* counts  = (int*)(q1 + 4096);         // n
    int* offsets = counts + n;                // n+2 (even pad)
    int* cursor  = offsets + n + 2;           // n
    int* bsum    = cursor + n;                // nchunks+1, round to even
    int2* epair  = (int2*)(bsum + ((nchunks + 2) & ~1));  // e pairs (eid, src)
    unsigned short* XLh = (unsigned short*)(epair + e);   // n*128 bf16
    float* Z2 = XR;                           // alias: XR dead after k_gat

    const int* src = edge_index;
    const int* dst = edge_index + e;

    const int nwaves = 8192;  // 2048 blocks x 4 waves
    const int nstats = 1024 + 8192;

    k_prep<<<(3 * 128 * 128 + n + nstats + 255) / 256, 256, 0, stream>>>(conv_w, wT, counts, stats, n, nstats);
    k_gemm_xlxr<<<(n + 63) / 64, 256, 0, stream>>>(x, W_l, b_l, W_r, b_r, XR, XLh, n);
    k_hist<<<(e + 255) / 256, 256, 0, stream>>>(dst, counts, e);
    k_scan1<<<nchunks, 256, 0, stream>>>(counts, offsets, bsum, n);
    k_scan2<<<1, 1024, 0, stream>>>(bsum, nchunks);
    k_scan3<<<(n + 256) / 256, 256, 0, stream>>>(offsets, cursor, bsum, n, nchunks);
    k_scatter<<<(e + 255) / 256, 256, 0, stream>>>(src, dst, cursor, epair, e);
    k_gat<<<nwaves / 4, 256, 0, stream>>>(XLh, XR, x, epair, offsets,
                                          edge_attr, W_e, att, bias_gat, weight1, Z,
                                          p1, q1, n, nwaves);
    k_bn_finish<<<1, 128, 0, stream>>>(p1, q1, bn1_gamma, bn1_beta, scale1, shift1, n, 32);
    k_conv<<<(n + 63) / 64, 512, 0, stream>>>(Z, scale1, shift1, wT, conv_b, weight2, Z2,
                                              sums2, sumsq2, n);
    k_bn_finish<<<1, 128, 0, stream>>>(sums2, sumsq2, bn2_gamma, bn2_beta, scale2, shift2, n, 1);
    k_final<<<(n * 32 + 255) / 256, 256, 0, stream>>>(Z2, scale2, shift2, (float*)d_out, n * 32);
}

// Round 13
// 526.408 us; speedup vs baseline: 1.1751x; 1.0652x over previous
//
#include <hip/hip_runtime.h>
#include <hip/hip_bf16.h>
#include <math.h>

#define DD 128
#define EPSBN 1e-5f

typedef float f2 __attribute__((ext_vector_type(2)));

// ---------- small helpers ----------
__device__ __forceinline__ float4 f4_add(float4 a, float4 b) {
    return make_float4(a.x + b.x, a.y + b.y, a.z + b.z, a.w + b.w);
}
__device__ __forceinline__ float4 f4_fma(float a, float4 b, float4 c) {
    c.x = fmaf(a, b.x, c.x); c.y = fmaf(a, b.y, c.y);
    c.z = fmaf(a, b.z, c.z); c.w = fmaf(a, b.w, c.w);
    return c;
}
__device__ __forceinline__ float leakyf(float v, float s) { return v > 0.f ? v : s * v; }

__device__ __forceinline__ unsigned short f2bf(float f) {   // RNE
    unsigned u = __float_as_uint(f);
    return (unsigned short)((u + 0x7fffu + ((u >> 16) & 1u)) >> 16);
}
__device__ __forceinline__ f2 bfu2f2(unsigned u) {          // packed 2×bf16 -> 2×f32
    f2 r;
    r.x = __uint_as_float(u << 16);
    r.y = __uint_as_float(u & 0xFFFF0000u);
    return r;
}
__device__ __forceinline__ f2 leaky2(f2 v, float s) {
    f2 z = (f2)0.f;
    return __builtin_elementwise_max(v, z) + s * __builtin_elementwise_min(v, z);
}

// ---------- prep: transpose conv_w AND zero counts/stats(+BN1 partials) ----------
__global__ __launch_bounds__(256) void k_prep(const float* __restrict__ conv_w, float* __restrict__ wT,
                                              int* __restrict__ counts, float* __restrict__ stats,
                                              int n, int nstats) {
    int idx = blockIdx.x * 256 + threadIdx.x;
    if (idx < 3 * 128 * 128) {
        int k = idx >> 14;
        int r = idx & 16383;
        int ci = r >> 7, co = r & 127;
        wT[idx] = conv_w[(size_t)co * 384 + ci * 3 + k];
    }
    int z = idx - 3 * 128 * 128;
    if (z >= 0) {
        if (z < n) counts[z] = 0;
        else if (z - n < nstats) stats[z - n] = 0.f;
    }
}

// ---------- XR = x@W_r + b_r (fp32); XLh = bf16(x@W_l + b_l) ----------
// R20: had the pre-R15 k_conv disease: 256 threads (12 waves/CU) + SCALAR As staging.
// Now 512 threads (8 waves/block, ~24 waves/CU; LDS 40KB -> 4 blocks/CU cap), 4 rows/thread,
// As staged as float4 (1/thread). Same 64x256 tile, same K-loop.
__global__ __launch_bounds__(512) void k_gemm_xlxr(
    const float* __restrict__ x, const float* __restrict__ Wl, const float* __restrict__ bl,
    const float* __restrict__ Wr, const float* __restrict__ br,
    float* __restrict__ XR, unsigned short* __restrict__ XLh, int n)
{
    __shared__ float As[64 * 32];    // 8 KB
    __shared__ float Bs[32 * 256];   // 32 KB
    int tid = threadIdx.x;           // 0..511
    int r0 = blockIdx.x * 64;
    int tx = tid & 31, ty = tid >> 5;   // ty 0..15
    int rbase = ty * 4;

    float4 accL[4], accR[4];
    #pragma unroll
    for (int j = 0; j < 4; ++j) {
        accL[j] = make_float4(0.f, 0.f, 0.f, 0.f);
        accR[j] = make_float4(0.f, 0.f, 0.f, 0.f);
    }

    for (int k0 = 0; k0 < 128; k0 += 32) {
        // stage As: 64 rows x 32 k = 512 float4, one per thread
        {
            int lrow = tid >> 3, k4 = (tid & 7) * 4;
            int g = r0 + lrow;
            float4 v = make_float4(0.f, 0.f, 0.f, 0.f);
            if (g < n) v = *(const float4*)(x + (size_t)g * DD + k0 + k4);
            *(float4*)(As + lrow * 32 + k4) = v;
        }
        // stage Bs: 32 k x 256 co = 2048 float4, 4 per thread, coalesced
        #pragma unroll
        for (int s = 0; s < 4; ++s) {
            int idx = s * 512 + tid;
            int kk = idx >> 6, co4 = idx & 63;
            float4 v;
            if (co4 < 32) v = ((const float4*)Wl)[(size_t)(k0 + kk) * 32 + co4];
            else          v = ((const float4*)Wr)[(size_t)(k0 + kk) * 32 + (co4 - 32)];
            ((float4*)Bs)[kk * 64 + co4] = v;
        }
        __syncthreads();

        #pragma unroll 4
        for (int kk = 0; kk < 32; ++kk) {
            float a[4];
            #pragma unroll
            for (int j = 0; j < 4; ++j) a[j] = As[(rbase + j) * 32 + kk];
            float4 bL = ((float4*)Bs)[kk * 64 + tx];
            float4 bR = ((float4*)Bs)[kk * 64 + 32 + tx];
            #pragma unroll
            for (int j = 0; j < 4; ++j) {
                accL[j] = f4_fma(a[j], bL, accL[j]);
                accR[j] = f4_fma(a[j], bR, accR[j]);
            }
        }
        __syncthreads();
    }

    float4 blv = ((const float4*)bl)[tx];
    float4 brv = ((const float4*)br)[tx];
    #pragma unroll
    for (int j = 0; j < 4; ++j) {
        int row = r0 + rbase + j;
        if (row < n) {
            float4 L4 = f4_add(accL[j], blv);
            ((float4*)(XR + (size_t)row * DD))[tx] = f4_add(accR[j], brv);
            uint2 hp;
            hp.x = (unsigned)f2bf(L4.x) | ((unsigned)f2bf(L4.y) << 16);
            hp.y = (unsigned)f2bf(L4.z) | ((unsigned)f2bf(L4.w) << 16);
            ((uint2*)(XLh + (size_t)row * DD))[tx] = hp;
        }
    }
}

// ---------- CSR build ----------
__global__ __launch_bounds__(256) void k_hist(const int* __restrict__ dst, int* __restrict__ counts, int e) {
    int idx = blockIdx.x * 256 + threadIdx.x;
    if (idx < e) atomicAdd(&counts[dst[idx]], 1);
}

// 3-stage parallel scan: chunk-local scan -> chunk-sum scan -> add-back
__global__ __launch_bounds__(256) void k_scan1(const int* __restrict__ counts,
                                               int* __restrict__ offsets, int* __restrict__ bsum, int n) {
    __shared__ int tmp[256];
    int t = threadIdx.x;
    int i = blockIdx.x * 256 + t;
    int v = (i < n) ? counts[i] : 0;
    tmp[t] = v;
    __syncthreads();
    for (int off = 1; off < 256; off <<= 1) {
        int u = (t >= off) ? tmp[t - off] : 0;
        __syncthreads();
        tmp[t] += u;
        __syncthreads();
    }
    if (i < n) offsets[i] = tmp[t] - v;          // exclusive within chunk
    if (t == 255) bsum[blockIdx.x] = tmp[255];   // chunk total
}

__global__ __launch_bounds__(1024) void k_scan2(int* __restrict__ bsum, int nchunks) {
    __shared__ int tmp[1024];
    int t = threadIdx.x;
    int v = (t < nchunks) ? bsum[t] : 0;
    tmp[t] = v;
    __syncthreads();
    for (int off = 1; off < 1024; off <<= 1) {
        int u = (t >= off) ? tmp[t - off] : 0;
        __syncthreads();
        tmp[t] += u;
        __syncthreads();
    }
    if (t < nchunks) bsum[t] = tmp[t] - v;       // exclusive chunk prefix
    if (t == 0) bsum[nchunks] = tmp[nchunks - 1]; // grand total
}

__global__ __launch_bounds__(256) void k_scan3(int* __restrict__ offsets, int* __restrict__ cursor,
                                               const int* __restrict__ bsum, int n, int nchunks) {
    int i = blockIdx.x * 256 + threadIdx.x;
    if (i < n) {
        int o = offsets[i] + bsum[i >> 8];
        offsets[i] = o;
        cursor[i] = o;
    }
    if (i == n) offsets[n] = bsum[nchunks];
}

__global__ __launch_bounds__(256) void k_scatter(const int* __restrict__ src, const int* __restrict__ dst,
                                                 int* __restrict__ cursor, int2* __restrict__ epair, int e) {
    int idx = blockIdx.x * 256 + threadIdx.x;
    if (idx >= e) return;
    int d = dst[idx];
    int pos = atomicAdd(&cursor[d], 1);
    epair[pos] = make_int2(idx, src[idx]);
}

// ---------- fused GATv2: wave-per-node (grid-strided), no-max softmax, single gather pass ----------
// exp(l) without max subtraction is safe: logit sigma ~1.5, max over 850k edges ~8 << 88.
// R8's measured-best structure (138.6us): 4-edge groups, depth-1 2-buffer ping-pong,
// write-late attr staging, serial tail, fused BN1 stats w/ 32-slot partials.
// R19/R20 NOTE: k_gat ~138us is this algorithm's floor — depth-2 (x2 variants) and
// dual-stream all null/regressed; BW pins at ~1.75 TB/s (random 256B gather throughput).

#define EPROJ(EB_, J_, EV_) {                                                   \
    const float4* e4_ = ((const float4*)(EB_)) + (J_) * 4;                      \
    float4 a0_ = e4_[0], a1_ = e4_[1], a2_ = e4_[2], a3_ = e4_[3];              \
    f2 v_ = (f2)0.f;                                                            \
    v_ = __builtin_elementwise_fma((f2)a0_.x, w2[0],  v_);                      \
    v_ = __builtin_elementwise_fma((f2)a0_.y, w2[1],  v_);                      \
    v_ = __builtin_elementwise_fma((f2)a0_.z, w2[2],  v_);                      \
    v_ = __builtin_elementwise_fma((f2)a0_.w, w2[3],  v_);                      \
    v_ = __builtin_elementwise_fma((f2)a1_.x, w2[4],  v_);                      \
    v_ = __builtin_elementwise_fma((f2)a1_.y, w2[5],  v_);                      \
    v_ = __builtin_elementwise_fma((f2)a1_.z, w2[6],  v_);                      \
    v_ = __builtin_elementwise_fma((f2)a1_.w, w2[7],  v_);                      \
    v_ = __builtin_elementwise_fma((f2)a2_.x, w2[8],  v_);                      \
    v_ = __builtin_elementwise_fma((f2)a2_.y, w2[9],  v_);                      \
    v_ = __builtin_elementwise_fma((f2)a2_.z, w2[10], v_);                      \
    v_ = __builtin_elementwise_fma((f2)a2_.w, w2[11], v_);                      \
    v_ = __builtin_elementwise_fma((f2)a3_.x, w2[12], v_);                      \
    v_ = __builtin_elementwise_fma((f2)a3_.y, w2[13], v_);                      \
    v_ = __builtin_elementwise_fma((f2)a3_.z, w2[14], v_);                      \
    v_ = __builtin_elementwise_fma((f2)a3_.w, w2[15], v_);                      \
    EV_ = v_; }

#define GAT_LOAD4(q_, U0_, U1_, U2_, U3_, AV_) {                                \
    int2 g0_ = epair[q_], g1_ = epair[(q_) + 1];                                \
    int2 g2_ = epair[(q_) + 2], g3_ = epair[(q_) + 3];                          \
    int s0_ = __builtin_amdgcn_readfirstlane(g0_.y);                            \
    int s1_ = __builtin_amdgcn_readfirstlane(g1_.y);                            \
    int s2_ = __builtin_amdgcn_readfirstlane(g2_.y);                            \
    int s3_ = __builtin_amdgcn_readfirstlane(g3_.y);                            \
    U0_ = XLu[(size_t)s0_ * 64 + lane];                                         \
    U1_ = XLu[(size_t)s1_ * 64 + lane];                                         \
    U2_ = XLu[(size_t)s2_ * 64 + lane];                                         \
    U3_ = XLu[(size_t)s3_ * 64 + lane];                                         \
    int ej_ = esel == 0 ? g0_.x : esel == 1 ? g1_.x : esel == 2 ? g2_.x : g3_.x;\
    AV_ = edge_attr[(size_t)ej_ * 16 + ek]; }

#define GAT_COMPUTE4(U0_, U1_, U2_, U3_, EB_) {                                 \
    f2 x0_ = bfu2f2(U0_), x1_ = bfu2f2(U1_);                                    \
    f2 x2_ = bfu2f2(U2_), x3_ = bfu2f2(U3_);                                    \
    f2 ev0_, ev1_, ev2_, ev3_;                                                  \
    EPROJ(EB_, 0, ev0_); EPROJ(EB_, 1, ev1_);                                   \
    EPROJ(EB_, 2, ev2_); EPROJ(EB_, 3, ev3_);                                   \
    f2 m0_ = leaky2(x0_ + xr2 + ev0_, 0.2f);                                    \
    f2 m1_ = leaky2(x1_ + xr2 + ev1_, 0.2f);                                    \
    f2 m2_ = leaky2(x2_ + xr2 + ev2_, 0.2f);                                    \
    f2 m3_ = leaky2(x3_ + xr2 + ev3_, 0.2f);                                    \
    float l0_ = m0_.x * att2.x + m0_.y * att2.y;                                \
    float l1_ = m1_.x * att2.x + m1_.y * att2.y;                                \
    float l2_ = m2_.x * att2.x + m2_.y * att2.y;                                \
    float l3_ = m3_.x * att2.x + m3_.y * att2.y;                                \
    _Pragma("unroll")                                                           \
    for (int off_ = 32; off_ > 0; off_ >>= 1) {                                 \
        l0_ += __shfl_xor(l0_, off_, 64);                                       \
        l1_ += __shfl_xor(l1_, off_, 64);                                       \
        l2_ += __shfl_xor(l2_, off_, 64);                                       \
        l3_ += __shfl_xor(l3_, off_, 64);                                       \
    }                                                                           \
    float g0_ = __expf(l0_), g1_ = __expf(l1_);                                 \
    float g2_ = __expf(l2_), g3_ = __expf(l3_);                                 \
    S += (g0_ + g1_) + (g2_ + g3_);                                             \
    axy = __builtin_elementwise_fma((f2)g0_, x0_, axy);                         \
    axy = __builtin_elementwise_fma((f2)g1_, x1_, axy);                         \
    axy = __builtin_elementwise_fma((f2)g2_, x2_, axy);                         \
    axy = __builtin_elementwise_fma((f2)g3_, x3_, axy); }

__global__ __launch_bounds__(256) void k_gat(
    const unsigned short* __restrict__ XLh, const float* __restrict__ XR,
    const float* __restrict__ x,
    const int2* __restrict__ epair, const int* __restrict__ offsets,
    const float* __restrict__ edge_attr, const float* __restrict__ We,
    const float* __restrict__ att, const float* __restrict__ bias_gat,
    const float* __restrict__ weight1, float* __restrict__ Z,
    float* __restrict__ p1, float* __restrict__ q1, int n, int nwaves)
{
    __shared__ float ebuf[4][2][64];   // [wave][buf][4 edges * 16 attrs]
    __shared__ f2 brs[4][64];          // BN1 stats block reduce
    __shared__ f2 brq[4][64];
    int wv   = threadIdx.x >> 6;
    int wid  = blockIdx.x * 4 + wv;
    int lane = threadIdx.x & 63;
    int c = lane * 2;
    int esel = lane >> 4, ek = lane & 15;
    const unsigned* __restrict__ XLu = (const unsigned*)XLh;
    float* ebA = &ebuf[wv][0][0];
    float* ebB = &ebuf[wv][1][0];

    f2 w2[16];
    #pragma unroll
    for (int k = 0; k < 16; ++k) w2[k] = *(const f2*)(We + k * DD + c);
    f2 att2 = *(const f2*)(att + c);
    f2 bg   = *(const f2*)(bias_gat + c);
    float w0 = weight1[0], w1v = weight1[1];
    float mw = fmaxf(w0, w1v);
    float e0w = __expf(w0 - mw), e1w = __expf(w1v - mw);
    float winv = 1.f / (e0w + e1w);
    float w1x = e0w * winv, w1a = e1w * winv;

    f2 bns = (f2)0.f, bnq = (f2)0.f;   // BN1 per-lane column stats

    for (int i = wid; i < n; i += nwaves) {
        f2 xr2 = *(const f2*)(XR + (size_t)i * DD + c);
        f2 xli = bfu2f2(XLu[(size_t)i * 64 + lane]);

        // self loop (e contribution is 0)
        f2 ms = leaky2(xli + xr2, 0.2f);
        float sl = ms.x * att2.x + ms.y * att2.y;
        #pragma unroll
        for (int off = 32; off > 0; off >>= 1) sl += __shfl_xor(sl, off, 64);
        float gs = __expf(sl);
        float S = gs;
        f2 axy = gs * xli;

        int p  = __builtin_amdgcn_readfirstlane(offsets[i]);
        int pe = __builtin_amdgcn_readfirstlane(offsets[i + 1]);
        int cnt = pe - p;
        int ng = cnt >> 2;

        if (ng > 0) {
            unsigned uA0, uA1, uA2, uA3, uB0, uB1, uB2, uB3;
            float avA, avB;
            GAT_LOAD4(p, uA0, uA1, uA2, uA3, avA);
            ebA[lane] = avA;                       // prologue stage (vmcnt stall once)
            int t = 0;
            for (;;) {
                bool mA = (t + 1 < ng);
                if (mA) GAT_LOAD4(p + 4 * (t + 1), uB0, uB1, uB2, uB3, avB);
                GAT_COMPUTE4(uA0, uA1, uA2, uA3, ebA);
                if (mA) ebB[lane] = avB;           // write-late: vmcnt hidden by compute
                if (++t >= ng) break;
                bool mB = (t + 1 < ng);
                if (mB) GAT_LOAD4(p + 4 * (t + 1), uA0, uA1, uA2, uA3, avA);
                GAT_COMPUTE4(uB0, uB1, uB2, uB3, ebB);
                if (mB) ebA[lane] = avA;
                if (++t >= ng) break;
            }
        }
        for (int q = p + (ng << 2); q < pe; ++q) {   // tail 0-3 edges
            int2 ej = epair[q];
            int eid = __builtin_amdgcn_readfirstlane(ej.x);
            int srn = __builtin_amdgcn_readfirstlane(ej.y);
            unsigned u = XLu[(size_t)srn * 64 + lane];
            const float* pa = edge_attr + (size_t)eid * 16;
            f2 ev = (f2)0.f;
            #pragma unroll
            for (int k = 0; k < 16; ++k) ev = __builtin_elementwise_fma((f2)pa[k], w2[k], ev);
            f2 x0 = bfu2f2(u);
            f2 m = leaky2(x0 + xr2 + ev, 0.2f);
            float l = m.x * att2.x + m.y * att2.y;
            #pragma unroll
            for (int off = 32; off > 0; off >>= 1) l += __shfl_xor(l, off, 64);
            float g = __expf(l);
            S += g;
            axy = __builtin_elementwise_fma((f2)g, x0, axy);
        }

        float rl = 1.f / S;
        f2 av = axy * rl + bg;
        f2 xv = *(const f2*)(x + (size_t)i * DD + c);
        f2 zv = w1x * xv + w1a * av;
        *(f2*)(Z + (size_t)i * DD + c) = zv;
        bns += zv;
        bnq = __builtin_elementwise_fma(zv, zv, bnq);
    }

    // BN1 stats: block reduce (4 waves), then atomics into 32-way partial slots
    // (chain depth 2048/32 = 64 per address -> negligible tail)
    brs[wv][lane] = bns;
    brq[wv][lane] = bnq;
    __syncthreads();
    if (threadIdx.x < 64) {
        f2 s = brs[0][lane] + brs[1][lane] + brs[2][lane] + brs[3][lane];
        f2 q = brq[0][lane] + brq[1][lane] + brq[2][lane] + brq[3][lane];
        int bbase = (blockIdx.x & 31) * 128 + c;
        atomicAdd(&p1[bbase], s.x); atomicAdd(&p1[bbase + 1], s.y);
        atomicAdd(&q1[bbase], q.x); atomicAdd(&q1[bbase + 1], q.y);
    }
}

// nparts: number of 128-wide partial slots to reduce (32 for BN1, 1 for BN2)
__global__ __launch_bounds__(128) void k_bn_finish(const float* __restrict__ sums, const float* __restrict__ sumsq,
                                                   const float* __restrict__ gamma, const float* __restrict__ beta,
                                                   float* __restrict__ scale, float* __restrict__ shift,
                                                   int n, int nparts) {
    int t = threadIdx.x;
    if (t >= 128) return;
    float s = 0.f, q = 0.f;
    for (int pp = 0; pp < nparts; ++pp) {
        s += sums[pp * 128 + t];
        q += sumsq[pp * 128 + t];
    }
    float fn = (float)n;
    float mu = s / fn;
    float var = q / fn - mu * mu;
    float rstd = rsqrtf(var + EPSBN);
    float sc = gamma[t] * rstd;
    scale[t] = sc;
    shift[t] = fmaf(-mu, sc, beta[t]);
}

// ---------- conv1d(k=3) tiled GEMM: 64 rows x 128 co, 512 threads; fused BN2 stats ----------
// 64-row tiles (Bs traffic 153MB total) with 8 waves/block: 782 blocks x 8 waves ->
// ~24 waves/CU, LDS ~30KB. (32-row tiles regressed: doubled staging+barriers.)
__global__ __launch_bounds__(512) void k_conv(
    const float* __restrict__ Z, const float* __restrict__ scale1, const float* __restrict__ shift1,
    const float* __restrict__ wT, const float* __restrict__ conv_b,
    const float* __restrict__ weight2, float* __restrict__ Z2,
    float* __restrict__ sums2, float* __restrict__ sumsq2, int n)
{
    __shared__ float As[66 * 20];        // 5280 B
    __shared__ float Bs[3 * 16 * 128];   // 24576 B
    int tid = threadIdx.x;               // 0..511
    int r0 = blockIdx.x * 64;
    int tx = tid & 31, ty = tid >> 5;    // ty 0..15
    int rbase = ty * 4;

    float4 acc[4];
    #pragma unroll
    for (int j = 0; j < 4; ++j) acc[j] = make_float4(0.f, 0.f, 0.f, 0.f);

    for (int ci0 = 0; ci0 < 128; ci0 += 16) {
        // stage As: 66 rows x 16 ci = 264 float4, single pass over 512 threads
        if (tid < 264) {
            int lrow = tid >> 2, c4 = (tid & 3) * 4;
            int g = r0 - 1 + lrow;
            int cc = ci0 + c4;
            float4 v = make_float4(0.f, 0.f, 0.f, 0.f);
            if (g >= 0 && g < n) {
                float4 zv = *(const float4*)(Z + (size_t)g * DD + cc);
                const float4 s4v = *(const float4*)(scale1 + cc);
                const float4 h4v = *(const float4*)(shift1 + cc);
                v.x = fmaf(zv.x, s4v.x, h4v.x); v.y = fmaf(zv.y, s4v.y, h4v.y);
                v.z = fmaf(zv.z, s4v.z, h4v.z); v.w = fmaf(zv.w, s4v.w, h4v.w);
            }
            *(float4*)(As + lrow * 20 + c4) = v;
        }
        // stage Bs: 3 k x 16 ci x 128 co = 1536 float4 (3 per thread), coalesced
        #pragma unroll
        for (int s = 0; s < 3; ++s) {
            int idx = s * 512 + tid;
            int k = idx >> 9;            // /512
            int r = idx & 511;
            int ci = r >> 5, co4 = r & 31;
            ((float4*)Bs)[idx] = ((const float4*)wT)[(size_t)k * 4096 + (ci0 + ci) * 32 + co4];
        }
        __syncthreads();

        #pragma unroll 2
        for (int ci = 0; ci < 16; ++ci) {
            float a[6];
            #pragma unroll
            for (int j = 0; j < 6; ++j) a[j] = As[(rbase + j) * 20 + ci];
            float4 b0 = ((float4*)Bs)[(0 * 16 + ci) * 32 + tx];
            float4 b1 = ((float4*)Bs)[(1 * 16 + ci) * 32 + tx];
            float4 b2 = ((float4*)Bs)[(2 * 16 + ci) * 32 + tx];
            #pragma unroll
            for (int j = 0; j < 4; ++j) {
                acc[j] = f4_fma(a[j],     b0, acc[j]);
                acc[j] = f4_fma(a[j + 1], b1, acc[j]);
                acc[j] = f4_fma(a[j + 2], b2, acc[j]);
            }
        }
        __syncthreads();
    }

    float w0 = weight2[0], w1v = weight2[1];
    float mw = fmaxf(w0, w1v);
    float e0 = __expf(w0 - mw), e1 = __expf(w1v - mw);
    float winv = 1.f / (e0 + e1);
    float w2x = e0 * winv, w2a = e1 * winv;

    float4 cb = ((const float4*)conv_b)[tx];
    float4 sc1 = ((const float4*)scale1)[tx];
    float4 sh1 = ((const float4*)shift1)[tx];
    float4 s4 = make_float4(0.f, 0.f, 0.f, 0.f), q4 = s4;
    #pragma unroll
    for (int j = 0; j < 4; ++j) {
        int row = r0 + rbase + j;
        if (row >= n) break;
        float4 z1 = f4_add(acc[j], cb);
        z1.x = leakyf(z1.x, 0.01f); z1.y = leakyf(z1.y, 0.01f);
        z1.z = leakyf(z1.z, 0.01f); z1.w = leakyf(z1.w, 0.01f);
        float4 zv = ((const float4*)(Z + (size_t)row * DD))[tx];
        float4 zbn;
        zbn.x = fmaf(zv.x, sc1.x, sh1.x); zbn.y = fmaf(zv.y, sc1.y, sh1.y);
        zbn.z = fmaf(zv.z, sc1.z, sh1.z); zbn.w = fmaf(zv.w, sc1.w, sh1.w);
        float4 o;
        o.x = w2x * zbn.x + w2a * z1.x; o.y = w2x * zbn.y + w2a * z1.y;
        o.z = w2x * zbn.z + w2a * z1.z; o.w = w2x * zbn.w + w2a * z1.w;
        ((float4*)(Z2 + (size_t)row * DD))[tx] = o;
        s4 = f4_add(s4, o);
        q4.x = fmaf(o.x, o.x, q4.x); q4.y = fmaf(o.y, o.y, q4.y);
        q4.z = fmaf(o.z, o.z, q4.z); q4.w = fmaf(o.w, o.w, q4.w);
    }

    // fused BN2 stats: reduce over ty (16) in LDS (Bs dead: 1024 float4 = 16KB <= 24KB)
    float4* rs = (float4*)Bs;          // 512 float4
    float4* rq = rs + 512;             // 512 float4
    rs[ty * 32 + tx] = s4;
    rq[ty * 32 + tx] = q4;
    __syncthreads();
    if (tid < 32) {
        float4 ts = rs[tid], tq = rq[tid];
        #pragma unroll
        for (int j = 1; j < 16; ++j) { ts = f4_add(ts, rs[j * 32 + tid]); tq = f4_add(tq, rq[j * 32 + tid]); }
        atomicAdd(&sums2[tid * 4 + 0], ts.x); atomicAdd(&sums2[tid * 4 + 1], ts.y);
        atomicAdd(&sums2[tid * 4 + 2], ts.z); atomicAdd(&sums2[tid * 4 + 3], ts.w);
        atomicAdd(&sumsq2[tid * 4 + 0], tq.x); atomicAdd(&sumsq2[tid * 4 + 1], tq.y);
        atomicAdd(&sumsq2[tid * 4 + 2], tq.z); atomicAdd(&sumsq2[tid * 4 + 3], tq.w);
    }
}

// ---------- final BN2 apply ----------
__global__ __launch_bounds__(256) void k_final(const float* __restrict__ Z2,
                                               const float* __restrict__ scale2, const float* __restrict__ shift2,
                                               float* __restrict__ out, int total4) {
    int idx = blockIdx.x * 256 + threadIdx.x;
    if (idx >= total4) return;
    int c4 = idx & 31;
    float4 v = ((const float4*)Z2)[idx];
    float4 sc = ((const float4*)scale2)[c4];
    float4 sh = ((const float4*)shift2)[c4];
    float4 r;
    r.x = fmaf(v.x, sc.x, sh.x); r.y = fmaf(v.y, sc.y, sh.y);
    r.z = fmaf(v.z, sc.z, sh.z); r.w = fmaf(v.w, sc.w, sh.w);
    ((float4*)out)[idx] = r;
}

extern "C" void kernel_launch(void* const* d_in, const int* in_sizes, int n_in,
                              void* d_out, int out_size, void* d_ws, size_t ws_size,
                              hipStream_t stream)
{
    const float* x          = (const float*)d_in[0];
    const int*   edge_index = (const int*)d_in[1];
    const float* edge_attr  = (const float*)d_in[2];
    const float* W_l        = (const float*)d_in[3];
    const float* b_l        = (const float*)d_in[4];
    const float* W_r        = (const float*)d_in[5];
    const float* b_r        = (const float*)d_in[6];
    const float* W_e        = (const float*)d_in[7];
    const float* att        = (const float*)d_in[8];
    const float* bias_gat   = (const float*)d_in[9];
    const float* weight1    = (const float*)d_in[10];
    const float* bn1_gamma  = (const float*)d_in[11];
    const float* bn1_beta   = (const float*)d_in[12];
    const float* conv_w     = (const float*)d_in[13];
    const float* conv_b     = (const float*)d_in[14];
    const float* weight2    = (const float*)d_in[15];
    const float* bn2_gamma  = (const float*)d_in[16];
    const float* bn2_beta   = (const float*)d_in[17];

    int n = in_sizes[0] / DD;   // 50000
    int e = in_sizes[1] / 2;    // 800000
    int nchunks = (n + 255) / 256;

    float* XR = (float*)d_ws;                 // n*128 f32
    float* Z  = XR + (size_t)n * DD;          // n*128 f32
    float* wT = Z + (size_t)n * DD;           // 3*128*128
    float* stats = wT + 49152;                // 1024 + 8192 floats (zeroed in k_prep)
    float* sums2 = stats + 256, *sumsq2 = stats + 384;
    float* scale1 = stats + 512, *shift1 = stats + 640;
    float* scale2 = stats + 768, *shift2 = stats + 896;
    float* p1 = stats + 1024;                 // [32][128] BN1 sum partials
    float* q1 = p1 + 4096;                    // [32][128] BN1 sumsq partials
    int* counts  = (int*)(q1 + 4096);         // n
    int* offsets = counts + n;                // n+2 (even pad)
    int* cursor  = offsets + n + 2;           // n
    int* bsum    = cursor + n;                // nchunks+1, round to even
    int2* epair  = (int2*)(bsum + ((nchunks + 2) & ~1));  // e pairs (eid, src)
    unsigned short* XLh = (unsigned short*)(epair + e);   // n*128 bf16
    float* Z2 = XR;                           // alias: XR dead after k_gat

    const int* src = edge_index;
    const int* dst = edge_index + e;

    const int nwaves = 8192;  // 2048 blocks x 4 waves
    const int nstats = 1024 + 8192;

    k_prep<<<(3 * 128 * 128 + n + nstats + 255) / 256, 256, 0, stream>>>(conv_w, wT, counts, stats, n, nstats);
    k_gemm_xlxr<<<(n + 63) / 64, 512, 0, stream>>>(x, W_l, b_l, W_r, b_r, XR, XLh, n);
    k_hist<<<(e + 255) / 256, 256, 0, stream>>>(dst, counts, e);
    k_scan1<<<nchunks, 256, 0, stream>>>(counts, offsets, bsum, n);
    k_scan2<<<1, 1024, 0, stream>>>(bsum, nchunks);
    k_scan3<<<(n + 256) / 256, 256, 0, stream>>>(offsets, cursor, bsum, n, nchunks);
    k_scatter<<<(e + 255) / 256, 256, 0, stream>>>(src, dst, cursor, epair, e);
    k_gat<<<nwaves / 4, 256, 0, stream>>>(XLh, XR, x, epair, offsets,
                                          edge_attr, W_e, att, bias_gat, weight1, Z,
                                          p1, q1, n, nwaves);
    k_bn_finish<<<1, 128, 0, stream>>>(p1, q1, bn1_gamma, bn1_beta, scale1, shift1, n, 32);
    k_conv<<<(n + 63) / 64, 512, 0, stream>>>(Z, scale1, shift1, wT, conv_b, weight2, Z2,
                                              sums2, sumsq2, n);
    k_bn_finish<<<1, 128, 0, stream>>>(sums2, sumsq2, bn2_gamma, bn2_beta, scale2, shift2, n, 1);
    k_final<<<(n * 32 + 255) / 256, 256, 0, stream>>>(Z2, scale2, shift2, (float*)d_out, n * 32);
}